// Round 11
// baseline (231.569 us; speedup 1.0000x reference)
//
#include <hip/hip_runtime.h>
#include <hip/hip_bf16.h>
#include <math.h>

// Problem constants
#define B_      4
#define S_      512
#define H_      768
#define NH_     4
#define DH_     192
#define N_      4096          // spans per batch
#define WD_     64
#define INNER_  3072
#define INDIM_  1600
#define SP1     513           // S+1 (CLS prepended)
#define ROWS_X  (B_*SP1)      // 2052
#define ROWS_XP 2176          // padded to multiple of 128
#define NSPAN   (B_*N_)       // 16384
#define KEYS_PB 41472         // 512*9*9 keys per batch
#define KEYSPACE (4*KEYS_PB)  // 165888 = 162*1024
#define MUPADMAX 16640        // 65*256

typedef __attribute__((ext_vector_type(8))) short bf16x8;
typedef __attribute__((ext_vector_type(4))) float f32x4;

__device__ __forceinline__ unsigned short f2bf(float f){
    unsigned u = __builtin_bit_cast(unsigned, f);
    u = u + 0x7FFFu + ((u >> 16) & 1u);   // round-to-nearest-even
    return (unsigned short)(u >> 16);
}
__device__ __forceinline__ float bf2f(unsigned hs){
    return __builtin_bit_cast(float, hs << 16);
}

__device__ __forceinline__ float wave_sum(float p){
    #pragma unroll
    for (int off = 32; off > 0; off >>= 1) p += __shfl_down(p, off);
    return p;
}

// async global->LDS, 16B per lane. lds must be wave-uniform; g is per-lane.
__device__ __forceinline__ void gld16(unsigned short* lds, const unsigned short* g){
    __builtin_amdgcn_global_load_lds(
        (const __attribute__((address_space(1))) unsigned int*)(const void*)g,
        (__attribute__((address_space(3))) unsigned int*)(void*)lds,
        16, 0, 0);
}

__device__ __forceinline__ void wgbar(){
    asm volatile("" ::: "memory");
    __builtin_amdgcn_s_barrier();
    asm volatile("" ::: "memory");
}
#define VMW(n) asm volatile("s_waitcnt vmcnt(" #n ")" ::: "memory")

// ---------------------------------------------------------------------------
// 1. mega prep: conversions + precomputes + present-clear + u-precompute.
//    block ranges: [0,576) Wv | +2304 W2b | +2052 build_x | +3072 W1a
//    | +576 OutT | +768 BiasC | +768 WC | +1 mask-detect | +162 clear
//    | +12 u (q computed locally per head; old q-proj blocks deleted)
// ---------------------------------------------------------------------------
__global__ __launch_bounds__(256) void mega_prep(
    const float* __restrict__ token_reps, const float* __restrict__ cls_emb,
    const float* __restrict__ in_proj_w, const float* __restrict__ in_proj_b,
    const float* __restrict__ out_proj_w, const float* __restrict__ out_proj_b,
    const float* __restrict__ cls_reps, const float* __restrict__ wtab,
    const float* __restrict__ w1, const float* __restrict__ b1,
    const float* __restrict__ w2, const unsigned* __restrict__ masks,
    unsigned short* __restrict__ Xb, unsigned short* __restrict__ Wv,
    unsigned short* __restrict__ W2b, unsigned short* __restrict__ W1a,
    unsigned short* __restrict__ OutT, float* __restrict__ u,
    float* __restrict__ BiasC, float* __restrict__ WC, int* __restrict__ flag,
    unsigned* __restrict__ presentW)
{
    int b = blockIdx.x, t = threadIdx.x;
    __shared__ float tile[32][33];
    __shared__ float q_sh[192];
    __shared__ int s_any;
    int wave = t >> 6, lane = t & 63;

    if (b < 576){                                     // Wv conversion (rows 1536..2304)
        long i = (long)b * 256 + t;
        float4 v = ((const float4*)(in_proj_w + (size_t)1536 * H_))[i];
        ushort4 o; o.x = f2bf(v.x); o.y = f2bf(v.y); o.z = f2bf(v.z); o.w = f2bf(v.w);
        ((ushort4*)Wv)[i] = o;
    } else if ((b -= 576) < 2304){                    // W2b conversion
        long i = (long)b * 256 + t;
        float4 v = ((const float4*)w2)[i];
        ushort4 o; o.x = f2bf(v.x); o.y = f2bf(v.y); o.z = f2bf(v.z); o.w = f2bf(v.w);
        ((ushort4*)W2b)[i] = o;
    } else if ((b -= 2304) < 2052){                   // build X
        int r = b;
        int bb = r / SP1, s = r % SP1;
        const float* src = (s == 0) ? cls_emb : &token_reps[((long)bb * S_ + (s - 1)) * H_];
        for (int d = t; d < H_; d += 256)
            Xb[(long)r * H_ + d] = f2bf(src[d]);
    } else if ((b -= 2052) < 3072){                   // w1 cols [0,768) -> W1a
        if (t < 192){
            float4 v = ((const float4*)&w1[(long)b * INDIM_])[t];
            ushort4 o; o.x = f2bf(v.x); o.y = f2bf(v.y); o.z = f2bf(v.z); o.w = f2bf(v.w);
            ((ushort4*)&W1a[(long)b * 768])[t] = o;
        }
    } else if ((b -= 3072) < 576){                    // out_proj_w transpose-convert
        int bx = (b % 24) * 32, by = (b / 24) * 32;
        int tx = t & 31, ty = t >> 5;
        #pragma unroll
        for (int r = 0; r < 32; r += 8)
            tile[ty + r][tx] = out_proj_w[(long)(by + ty + r) * 768 + bx + tx];
        __syncthreads();
        #pragma unroll
        for (int r = 0; r < 32; r += 8)
            OutT[(long)(bx + ty + r) * 768 + by + tx] = f2bf(tile[tx][ty + r]);
    } else if ((b -= 576) < 768){                     // BiasC
        int i = b * 4 + wave;
        const float* row = &w1[(long)i * INDIM_];
        float p0 = 0.f, pb0 = 0.f, pb1 = 0.f, pb2 = 0.f, pb3 = 0.f;
        #pragma unroll
        for (int k0 = 0; k0 < 12; ++k0){
            int k = lane + 64*k0;
            p0 += out_proj_b[k] * row[k];
            float rv = row[832 + k];
            pb0 += cls_reps[0*H_ + k] * rv;
            pb1 += cls_reps[1*H_ + k] * rv;
            pb2 += cls_reps[2*H_ + k] * rv;
            pb3 += cls_reps[3*H_ + k] * rv;
        }
        p0 = wave_sum(p0); pb0 = wave_sum(pb0); pb1 = wave_sum(pb1);
        pb2 = wave_sum(pb2); pb3 = wave_sum(pb3);
        if (lane == 0){
            float base = b1[i] + p0;
            BiasC[0*INNER_ + i] = base + pb0;
            BiasC[1*INNER_ + i] = base + pb1;
            BiasC[2*INNER_ + i] = base + pb2;
            BiasC[3*INNER_ + i] = base + pb3;
        }
    } else if ((b -= 768) < 768){                     // WC
        int i = b * 4 + wave;
        float rv = w1[(long)i * INDIM_ + 768 + lane];
        #pragma unroll
        for (int w = 0; w < 9; ++w){
            float p = wave_sum(wtab[w * WD_ + lane] * rv);
            if (lane == 0) WC[w * INNER_ + i] = p;
        }
    } else if ((b -= 768) < 1){                       // mask encoding detect
        if (t == 0) s_any = 0;
        __syncthreads();
        int any = 0;
        for (int i = t; i < 4096; i += 256){
            unsigned v = masks[i];
            if (!(v == 0u || v == 1u || v == 0x3F800000u)) any = 1;
        }
        if (any) s_any = 1;
        __syncthreads();
        if (t == 0) *flag = s_any;
    } else if ((b -= 1) < 162){                       // present clear
        presentW[b * 256 + t] = 0u;
    } else {                                          // u precompute (12 blocks)
        int ub = b - 162;                             // 0..11
        int h = ub / 3;
        // q for head h, computed locally (q_j includes bias)
        for (int jj = wave; jj < 192; jj += 4){
            const float* wr = &in_proj_w[(long)(h*192 + jj) * H_];
            float p = 0.f;
            #pragma unroll
            for (int i = 0; i < 12; ++i) p += cls_emb[lane + 64*i] * wr[lane + 64*i];
            p = wave_sum(p);
            if (lane == 0) q_sh[jj] = p + in_proj_b[h*192 + jj];
        }
        __syncthreads();
        // u[idx] = sum_j q_h[j] * wk[h*192+j][k]
        int idx = ub * 256 + t;
        int k = idx % 768;
        float s = 0.f;
        for (int j = 0; j < 192; ++j)
            s += q_sh[j] * in_proj_w[(long)(768 + h*192 + j) * 768 + k];
        u[idx] = s;
        // c_h = q_h . bk_h  (first block of each head, wave 0)
        if ((ub % 3) == 0 && wave == 0){
            float p = 0.f;
            for (int j = lane; j < 192; j += 64) p += q_sh[j] * in_proj_b[768 + h*192 + j];
            p = wave_sum(p);
            if (lane == 0) u[3072 + h] = p;
        }
    }
}

// ---------------------------------------------------------------------------
// 2. gemm97 device body (128x128, BK=32, gld16 staging) — used by mid_kernel
// ---------------------------------------------------------------------------
template<int EPI>
__device__ __forceinline__ void gemm97_body(
    int bid, int nwg,
    const unsigned short* __restrict__ A, const unsigned short* __restrict__ Bm,
    const float* __restrict__ biasA, void* __restrict__ Cp,
    int M, int N, int K, int lda, int ldb, int ldc, int nbx,
    unsigned short* As, unsigned short* Bs)
{
    const int t = threadIdx.x, lane = t & 63, wave = t >> 6;
    const int wr = wave >> 1, wcid = wave & 1;

    int swz = ((nwg & 7) == 0) ? ((bid & 7) * (nwg >> 3) + (bid >> 3)) : bid;
    const int m0 = (swz / nbx) * 128;
    const int n0 = (swz % nbx) * 128;

    f32x4 acc[4][4];
    #pragma unroll
    for (int i = 0; i < 4; ++i)
        #pragma unroll
        for (int j = 0; j < 4; ++j)
            acc[i][j] = (f32x4){0.f, 0.f, 0.f, 0.f};

    const unsigned short* gA = A + (long)(m0 + wave*32 + (lane >> 2)) * lda + (lane & 3) * 8;
    const unsigned short* gB = Bm + (long)(n0 + wave*32 + (lane >> 2)) * ldb + (lane & 3) * 8;
    unsigned short* lA = &As[wave * 32 * 32];
    unsigned short* lB = &Bs[wave * 32 * 32];
    const long a16 = (long)16 * lda, b16 = (long)16 * ldb;

    for (int k0 = 0; k0 < K; k0 += 32){
        gld16(lA,       gA + k0);
        gld16(lA + 512, gA + a16 + k0);
        gld16(lB,       gB + k0);
        gld16(lB + 512, gB + b16 + k0);
        __syncthreads();

        bf16x8 af[4], bfr[4];
        #pragma unroll
        for (int f = 0; f < 4; ++f){
            af[f]  = *(const bf16x8*)&As[(wr*64 + f*16 + (lane & 15)) * 32 + (lane >> 4) * 8];
            bfr[f] = *(const bf16x8*)&Bs[(wcid*64 + f*16 + (lane & 15)) * 32 + (lane >> 4) * 8];
        }
        #pragma unroll
        for (int i = 0; i < 4; ++i)
            #pragma unroll
            for (int j = 0; j < 4; ++j)
                acc[i][j] = __builtin_amdgcn_mfma_f32_16x16x32_bf16(af[i], bfr[j], acc[i][j], 0, 0, 0);
        __syncthreads();
    }

    const int r0 = (lane >> 4) * 4;
    const int cc = lane & 15;
    #pragma unroll
    for (int i = 0; i < 4; ++i){
        int rowb = m0 + wr*64 + i*16 + r0;
        #pragma unroll
        for (int j = 0; j < 4; ++j){
            int col = n0 + wcid*64 + j*16 + cc;
            float cb = biasA ? biasA[col] : 0.f;
            #pragma unroll
            for (int r = 0; r < 4; ++r){
                long o = (long)(rowb + r) * ldc + col;
                float v = acc[i][j][r] + cb;
                if (EPI == 1) ((unsigned short*)Cp)[o] = f2bf(v);
                else          ((float*)Cp)[o] = v;
            }
        }
    }
}

// ---------------------------------------------------------------------------
// 3. mid kernel: [0,144) Wfuse GEMM | [144,246) VB GEMM | [246,2298) scores
//    | [2298,2362) dedup key mark (flag + cleared present from mega_prep)
// ---------------------------------------------------------------------------
__global__ __launch_bounds__(256) void mid_kernel(
    const unsigned short* __restrict__ W1a, const unsigned short* __restrict__ OutT,
    unsigned short* __restrict__ Wfuse,
    const unsigned short* __restrict__ Xb, const unsigned short* __restrict__ Wv,
    const float* __restrict__ bv, unsigned short* __restrict__ VB,
    const float* __restrict__ token_reps, const float* __restrict__ cls_emb,
    const float* __restrict__ u, float* __restrict__ SC,
    const int* __restrict__ span_ids, const void* __restrict__ masks,
    const int* __restrict__ flag, const int* __restrict__ span_widths,
    int* __restrict__ keyarr, unsigned char* __restrict__ present)
{
    __shared__ unsigned short As[128 * 32];
    __shared__ unsigned short Bs[128 * 32];
    int blk = blockIdx.x, t = threadIdx.x;
    if (blk < 144){
        gemm97_body<1>(blk, 144, W1a, OutT, nullptr, Wfuse,
                       INNER_, 768, 768, 768, 768, 768, 6, As, Bs);
    } else if (blk < 246){
        gemm97_body<1>(blk - 144, 102, Xb, Wv, bv, VB,
                       ROWS_XP, 768, 768, 768, 768, 768, 6, As, Bs);
    } else if (blk < 2298){
        int r = blk - 246;                            // 0..2051
        int b = r / SP1, s = r % SP1;
        const float* src = (s == 0) ? cls_emb : &token_reps[((long)b * S_ + (s - 1)) * H_];
        int h = t >> 6, lane = t & 63;
        float p = 0.f;
        #pragma unroll
        for (int i = 0; i < 12; ++i) p += src[lane + 64*i] * u[h*768 + lane + 64*i];
        p = wave_sum(p);
        if (lane == 0){
            const float scale = 0.0721687836487032f;  // 1/sqrt(192)
            SC[((long)(b * NH_ + h)) * SP1 + s] = (p + u[3072 + h]) * scale;
        }
    } else {                                          // dedup key mark
        int span = (blk - 2298) * 256 + t;
        int start = span_ids[span*2], end = span_ids[span*2+1];
        bool sm = (*flag == 0) ? (((const unsigned*)masks)[span] != 0u)
                               : (((const unsigned char*)masks)[span] != 0);
        int cnt = sm ? (end - start) : 0;
        if (cnt < 0) cnt = 0;
        if (cnt > 8) cnt = 8;
        if (start < 0) start = 0;
        if (start > 511) start = 511;
        if (start + cnt > S_) cnt = S_ - start;
        if (cnt == 0) start = 0;                     // masked-span collapse
        int w = span_widths[span];
        w = (w < 0) ? 0 : ((w > 8) ? 8 : w);
        int b = span >> 12;
        int key = b * KEYS_PB + (start * 9 + cnt) * 9 + w;
        keyarr[span] = key;
        present[key] = 1;
    }
}

// ---------------------------------------------------------------------------
// 4. scan: B (per-block counts) then D (local re-scan of counts + emit + mu)
// ---------------------------------------------------------------------------
__global__ __launch_bounds__(256) void scanB(const unsigned* __restrict__ present4,
                                             int* __restrict__ blockCnt){
    __shared__ int sh[256];
    int blk = blockIdx.x, t = threadIdx.x;
    unsigned w = present4[blk*256 + t];
    int c = (w & 1) + ((w >> 8) & 1) + ((w >> 16) & 1) + ((w >> 24) & 1);
    sh[t] = c; __syncthreads();
    for (int off = 128; off > 0; off >>= 1){
        if (t < off) sh[t] += sh[t + off];
        __syncthreads();
    }
    if (t == 0) blockCnt[blk] = sh[0];
}

__global__ __launch_bounds__(256) void scanD(const unsigned* __restrict__ present4,
                                             const int* __restrict__ blockCnt,
                                             int* __restrict__ slotOf, int* __restrict__ slotPack,
                                             int* __restrict__ widthsU, int* __restrict__ mu){
    __shared__ int offs[256];
    __shared__ int sh[256];
    int blk = blockIdx.x, t = threadIdx.x;
    int v = (t < 162) ? blockCnt[t] : 0;
    offs[t] = v; __syncthreads();
    for (int off = 1; off < 256; off <<= 1){
        int add = (t >= off) ? offs[t - off] : 0;
        __syncthreads();
        offs[t] += add;
        __syncthreads();
    }
    if (blk == 0 && t == 161){ mu[0] = offs[161]; mu[1] = (offs[161] + 255) & ~255; }
    int blockBase = (blk == 0) ? 0 : offs[blk - 1];
    unsigned w = present4[blk*256 + t];
    int c = (w & 1) + ((w >> 8) & 1) + ((w >> 16) & 1) + ((w >> 24) & 1);
    sh[t] = c; __syncthreads();
    for (int off = 1; off < 256; off <<= 1){
        int add = (t >= off) ? sh[t - off] : 0;
        __syncthreads();
        sh[t] += add;
        __syncthreads();
    }
    int slot = blockBase + sh[t] - c;
    #pragma unroll
    for (int i = 0; i < 4; ++i){
        if ((w >> (8*i)) & 1){
            int k = blk*1024 + t*4 + i;
            slotOf[k] = slot;
            int b = k / KEYS_PB, kl = k % KEYS_PB;
            int width = kl % 9, sc2 = kl / 9;
            int cnt = sc2 % 9, start = sc2 / 9;
            slotPack[slot] = start | (cnt << 9) | (width << 13) | (b << 17);
            widthsU[slot]  = width | (b << 4);
            slot++;
        }
    }
}

// ---------------------------------------------------------------------------
// 5. attn_spanmap: blocks [0,16640) unique-span attention; rest spanmap
// ---------------------------------------------------------------------------
__global__ __launch_bounds__(192) void attn_spanmap(
    const int* __restrict__ mu, const int* __restrict__ slotPack,
    const float* __restrict__ SC, const unsigned short* __restrict__ VB,
    unsigned short* __restrict__ CTXU,
    const int* __restrict__ keyarr, const int* __restrict__ slotOf,
    int* __restrict__ slotspan)
{
    int blk = blockIdx.x, t = threadIdx.x;
    if (blk >= MUPADMAX){                            // spanmap part
        int s = (blk - MUPADMAX) * 192 + t;
        if (s < NSPAN) slotspan[s] = slotOf[keyarr[s]];
        return;
    }
    int slot = blk;
    if (slot >= mu[0]) return;
    int pk = slotPack[slot];
    int start = pk & 511, cnt = (pk >> 9) & 15, b = (pk >> 17) & 3;
    __shared__ float w_sh[NH_][12];

    if (t < NH_){
        int h = t;
        const float* sc = &SC[((long)(b * NH_ + h)) * SP1];
        float m = sc[0];
        for (int j = 0; j < cnt; ++j) m = fmaxf(m, sc[1 + start + j]);
        float e0 = expf(sc[0] - m), sum = e0;
        float ej[8];
        for (int j = 0; j < cnt; ++j){ ej[j] = expf(sc[1 + start + j] - m); sum += ej[j]; }
        float inv = 1.f / sum;
        w_sh[h][0] = e0 * inv;
        for (int j = 0; j < cnt; ++j) w_sh[h][1 + j] = ej[j] * inv;
    }
    __syncthreads();

    long ctxbase = (long)slot * H_;
    const unsigned short* V0 = VB + (long)(b * SP1) * 768;
    #pragma unroll
    for (int i = 0; i < 2; ++i){
        int p = t + 192 * i;
        int d = p * 2;
        int h = d / DH_;
        float w0 = w_sh[h][0];
        unsigned v = ((const unsigned*)V0)[p];
        float a0 = w0 * bf2f(v & 0xffffu), a1 = w0 * bf2f(v >> 16);
        for (int j = 0; j < cnt; ++j){
            unsigned vv = *(const unsigned*)(V0 + (long)(1 + start + j) * 768 + d);
            float wj = w_sh[h][1 + j];
            a0 += wj * bf2f(vv & 0xffffu);
            a1 += wj * bf2f(vv >> 16);
        }
        ((unsigned*)(CTXU + ctxbase))[p] = (unsigned)f2bf(a0) | ((unsigned)f2bf(a1) << 16);
    }
}

// ---------------------------------------------------------------------------
// 6. gather_out3: out[span] = bf2f(P0[slot]) + bf2f(P1[slot]) + b2
// ---------------------------------------------------------------------------
__global__ __launch_bounds__(256) void gather_out3(
    const int* __restrict__ slotspan, const unsigned short* __restrict__ P0,
    const unsigned short* __restrict__ P1, const float* __restrict__ b2,
    float* __restrict__ out)
{
    const long total = (long)NSPAN * 192;            // float4 count
    long stride = (long)gridDim.x * 256;
    for (long idx = (long)blockIdx.x * 256 + threadIdx.x; idx < total; idx += stride){
        long s = idx / 192, d = idx % 192;
        long so = (long)slotspan[s] * 192 + d;
        ushort4 p0 = ((const ushort4*)P0)[so];
        ushort4 p1 = ((const ushort4*)P1)[so];
        float4 bb = ((const float4*)b2)[d];
        float4 o;
        o.x = bf2f(p0.x) + bf2f(p1.x) + bb.x;
        o.y = bf2f(p0.y) + bf2f(p1.y) + bb.y;
        o.z = bf2f(p0.z) + bf2f(p1.z) + bb.z;
        o.w = bf2f(p0.w) + bf2f(p1.w) + bb.w;
        ((float4*)out)[idx] = o;
    }
}

// ---------------------------------------------------------------------------
// 7. 256x256 GEMM v4 (one-phase-ahead prefetch). Early-exit on mu BEFORE the
//    XCD swizzle; bijective m204 swizzle over the active prefix.
//    EPI 2: bf16 out + relu + per-row packed width|batch bias
//    EPI 3: split-K dual; BOTH halves bf16: sp=0 -> Cp, sp=1 -> Cp1
// ---------------------------------------------------------------------------
template<int EPI, int LDA_, int LDB_>
__global__ __launch_bounds__(512, 2) void gemm256v4(
    const unsigned short* __restrict__ A, const unsigned short* __restrict__ Bm,
    const float* __restrict__ biasA, const float* __restrict__ biasB,
    const int* __restrict__ widths, void* __restrict__ Cp,
    int K, int ldc, int nbx, const int* __restrict__ mu,
    unsigned short* __restrict__ Cp1)
{
    __shared__ __align__(16) unsigned char lds[131072];
    const int t = threadIdx.x, lane = t & 63;
    const int wave = t >> 6;
    const int wr = wave >> 2, wc = wave & 3;      // 2M x 4N waves

    int nwg = gridDim.x, bid = blockIdx.x;
    int sp = 0;
    if (EPI == 3){
        int nh = nwg >> 1;
        sp = (bid >= nh) ? 1 : 0;
        bid -= sp * nh;
        nwg = nh;
    }
    if (mu){                                      // exit FIRST, swizzle over actives
        int nact = (mu[1] >> 8) * nbx;
        if (bid >= nact) return;
        nwg = nact;
    }
    // bijective m204 XCD swizzle over the active prefix
    int q = nwg >> 3, rr = nwg & 7;
    int xcd = bid & 7, idx8 = bid >> 3;
    int swz = (xcd < rr ? xcd * (q + 1) : rr * (q + 1) + (xcd - rr) * q) + idx8;
    const int m0 = (swz / nbx) * 256;
    const int n0 = (swz % nbx) * 256;

    const int Keff = (EPI == 3) ? (K >> 1) : K;
    const unsigned short* Ab = A + (EPI == 3 ? (long)sp * Keff : 0);
    const unsigned short* Bb = Bm + (EPI == 3 ? (long)sp * Keff : 0);

    // staging (source pre-swizzled; LDS dest linear, wave-private 1KB slices)
    const int rQ = t >> 3;
    const int cswz = ((t & 7) ^ (rQ & 7)) << 3;
    const unsigned short* sA = Ab + (long)(m0 + rQ) * LDA_ + cswz;
    const unsigned short* sB = Bb + (long)(n0 + ((rQ >> 5) * 64 + (rQ & 31))) * LDB_ + cswz;
    const int wsl = wave * 1024;

    // ds_read bases (16x16 fragments, conflict-free swizzle)
    const int aRow = (wr * 64 + (lane & 15)) * 128;
    const int bRow = (wc * 32 + (lane & 15)) * 128;
    const int pcl0 = (((lane >> 4) * 16)) ^ ((lane & 7) << 4);
    const int pcl1 = (64 + ((lane >> 4) * 16)) ^ ((lane & 7) << 4);

    f32x4 acc[8][4];
    #pragma unroll
    for (int i = 0; i < 8; ++i)
        #pragma unroll
        for (int j = 0; j < 4; ++j)
            acc[i][j] = (f32x4){0.f, 0.f, 0.f, 0.f};

    const int KT = Keff >> 6;
    bf16x8 aL[4][2], aH[4][2], bE[2][2], bO[2][2];

#define STG_(off, src) gld16((unsigned short*)(void*)(lds + (off) + wsl), (src))
#define RD_AL(fi, base) { aL[fi][0] = *(const bf16x8*)(lds + (base) + aRow + (fi)*2048 + pcl0); \
                          aL[fi][1] = *(const bf16x8*)(lds + (base) + aRow + (fi)*2048 + pcl1); }
#define RD_AH(fi, base) { aH[fi][0] = *(const bf16x8*)(lds + (base) + 16384 + aRow + (fi)*2048 + pcl0); \
                          aH[fi][1] = *(const bf16x8*)(lds + (base) + 16384 + aRow + (fi)*2048 + pcl1); }
#define RD_BE(jj, base) { bE[jj][0] = *(const bf16x8*)(lds + (base) + (jj)*2048 + bRow + pcl0); \
                          bE[jj][1] = *(const bf16x8*)(lds + (base) + (jj)*2048 + bRow + pcl1); }
#define RD_BO(jj, base) { bO[jj][0] = *(const bf16x8*)(lds + (base) + 16384 + (jj)*2048 + bRow + pcl0); \
                          bO[jj][1] = *(const bf16x8*)(lds + (base) + 16384 + (jj)*2048 + bRow + pcl1); }
#define Q_MFMA(AR, BR, I0, J0) \
    __builtin_amdgcn_s_setprio(1); \
    _Pragma("unroll") \
    for (int i = 0; i < 4; ++i) \
        _Pragma("unroll") \
        for (int j = 0; j < 2; ++j){ \
            acc[(I0)+i][(J0)+j] = __builtin_amdgcn_mfma_f32_16x16x32_bf16(AR[i][0], BR[j][0], acc[(I0)+i][(J0)+j], 0, 0, 0); \
            acc[(I0)+i][(J0)+j] = __builtin_amdgcn_mfma_f32_16x16x32_bf16(AR[i][1], BR[j][1], acc[(I0)+i][(J0)+j], 0, 0, 0); \
        } \
    __builtin_amdgcn_s_setprio(0);

    // ---- prologue: stage K-tile 0 (FIFO U1,U2,U3,U4); read aL[0,1], bE ----
    STG_(0,             sA);
    STG_(8192,          sA + 128 * LDA_);
    STG_(65536,         sB);
    STG_(65536 + 8192,  sB + 128 * LDB_);
    STG_(65536 + 16384, sB + 32 * LDB_);
    STG_(65536 + 24576, sB + 160 * LDB_);
    STG_(16384,         sA + 64 * LDA_);
    STG_(24576,         sA + 192 * LDA_);
    VMW(4);
    wgbar();
    RD_AL(0, 0u); RD_AL(1, 0u);
    RD_BE(0, 65536u); RD_BE(1, 65536u);

    for (int kt = 0; kt < KT - 1; ++kt){
        const unsigned rA = (unsigned)(kt & 1) * 32768u;
        const unsigned rB = 65536u + rA;
        const unsigned wA = rA ^ 32768u;
        const unsigned wB = 65536u + wA;
        const unsigned short* pA = sA + (long)(kt + 1) * 64;
        const unsigned short* pB = sB + (long)(kt + 1) * 64;

        // ===== P1
        VMW(2);
        STG_(wA, pA); STG_(wA + 8192, pA + 128 * LDA_);
        wgbar();
        RD_AL(2, rA); RD_AL(3, rA);
        RD_BO(0, rB); RD_BO(1, rB);
        Q_MFMA(aL, bE, 0, 0);

        // ===== P2
        VMW(2);
        STG_(wB, pB); STG_(wB + 8192, pB + 128 * LDB_);
        wgbar();
        RD_AH(0, rA); RD_AH(1, rA);
        Q_MFMA(aL, bO, 0, 2);

        // ===== P3
        STG_(wB + 16384, pB + 32 * LDB_); STG_(wB + 24576, pB + 160 * LDB_);
        wgbar();
        RD_AH(2, rA); RD_AH(3, rA);
        Q_MFMA(aH, bE, 4, 0);

        // ===== P4
        VMW(2);
        STG_(wA + 16384, pA + 64 * LDA_); STG_(wA + 24576, pA + 192 * LDA_);
        wgbar();
        RD_AL(0, wA); RD_AL(1, wA);
        RD_BE(0, wB); RD_BE(1, wB);
        Q_MFMA(aH, bO, 4, 2);
    }

    // ---- tail
    {
        const unsigned rA = (unsigned)((KT - 1) & 1) * 32768u;
        const unsigned rB = 65536u + rA;
        VMW(2);
        wgbar();
        RD_AL(2, rA); RD_AL(3, rA);
        RD_BO(0, rB); RD_BO(1, rB);
        Q_MFMA(aL, bE, 0, 0);
        VMW(0);
        wgbar();
        RD_AH(0, rA); RD_AH(1, rA);
        Q_MFMA(aL, bO, 0, 2);
        RD_AH(2, rA); RD_AH(3, rA);
        Q_MFMA(aH, bE, 4, 0);
        Q_MFMA(aH, bO, 4, 2);
    }
#undef STG_
#undef RD_AL
#undef RD_AH
#undef RD_BE
#undef RD_BO
#undef Q_MFMA

    // ---- epilogue via LDS routing; row = wr*128 + mq*64 + i*16 + r0 + r
    const int r0 = (lane >> 4) * 4;
    const int cc = lane & 15;
    const int Nn = nbx * 256;

    if (EPI == 2){
        wgbar();
        #pragma unroll
        for (int mq = 0; mq < 2; ++mq){
            #pragma unroll
            for (int i = 0; i < 4; ++i){
                #pragma unroll
                for (int r = 0; r < 4; ++r){
                    int row = wr*128 + mq*64 + i*16 + r0 + r;   // local 0..255
                    int wb = widths[m0 + row];                  // packed wv | b<<4
                    int wv = wb & 15, bb = (wb >> 4) & 3;
                    const float* bcl = biasA + (long)bb * Nn;
                    const float* wcb = biasB + (long)wv * Nn;
                    unsigned key = (unsigned)((row & 7) << 4);
                    unsigned rbase = (unsigned)row * 512u;
                    #pragma unroll
                    for (int j = 0; j < 4; ++j){
                        int col = wc*64 + j*16 + cc;
                        float v = acc[4*mq + i][j][r] + bcl[n0 + col] + wcb[n0 + col];
                        v = fmaxf(v, 0.f);
                        *(unsigned short*)(lds + rbase + (((unsigned)col * 2u) ^ key)) = f2bf(v);
                    }
                }
            }
        }
        wgbar();
        #pragma unroll
        for (int k = 0; k < 16; ++k){
            int row = (t >> 5) + k*16;
            int l32 = t & 31;
            bf16x8 val = *(const bf16x8*)(lds + (unsigned)row*512u
                             + (((unsigned)l32*16u) ^ ((unsigned)(row & 7) << 4)));
            *(bf16x8*)((unsigned short*)Cp + (long)(m0 + row) * ldc + n0 + l32*8) = val;
        }
    } else if (EPI == 3){
        // bf16 partial (both halves), no bias, no relu
        unsigned short* dst = sp ? Cp1 : (unsigned short*)Cp;
        wgbar();
        #pragma unroll
        for (int mq = 0; mq < 2; ++mq){
            #pragma unroll
            for (int i = 0; i < 4; ++i){
                #pragma unroll
                for (int r = 0; r < 4; ++r){
                    int row = wr*128 + mq*64 + i*16 + r0 + r;
                    unsigned key = (unsigned)((row & 7) << 4);
                    unsigned rbase = (unsigned)row * 512u;
                    #pragma unroll
                    for (int j = 0; j < 4; ++j){
                        int col = wc*64 + j*16 + cc;
                        *(unsigned short*)(lds + rbase + (((unsigned)col * 2u) ^ key))
                            = f2bf(acc[4*mq + i][j][r]);
                    }
                }
            }
        }
        wgbar();
        #pragma unroll
        for (int k = 0; k < 16; ++k){
            int row = (t >> 5) + k*16;
            int l32 = t & 31;
            bf16x8 val = *(const bf16x8*)(lds + (unsigned)row*512u
                             + (((unsigned)l32*16u) ^ ((unsigned)(row & 7) << 4)));
            *(bf16x8*)(dst + (long)(m0 + row) * ldc + n0 + l32*8) = val;
        }
    } else {
        // f32 out: two half-tile passes (wr==h owns storage rows)
        #pragma unroll
        for (int h = 0; h < 2; ++h){
            wgbar();
            if (wr == h){
                #pragma unroll
                for (int mq = 0; mq < 2; ++mq){
                    #pragma unroll
                    for (int i = 0; i < 4; ++i){
                        #pragma unroll
                        for (int r = 0; r < 4; ++r){
                            int rloc = mq*64 + i*16 + r0 + r;
                            unsigned key = (unsigned)((rloc & 7) << 4);
                            unsigned rbase = (unsigned)rloc * 1024u;
                            #pragma unroll
                            for (int j = 0; j < 4; ++j){
                                int col = wc*64 + j*16 + cc;
                                float v = acc[4*mq + i][j][r] + (biasA ? biasA[n0 + col] : 0.f);
                                *(float*)(lds + rbase + (((unsigned)col * 4u) ^ key)) = v;
                            }
                        }
                    }
                }
            }
            wgbar();
            #pragma unroll
            for (int k = 0; k < 16; ++k){
                int rloc = (t >> 6) + k*8;
                int l64 = t & 63;
                f32x4 val = *(const f32x4*)(lds + (unsigned)rloc*1024u
                                 + (((unsigned)l64*16u) ^ ((unsigned)(rloc & 7) << 4)));
                *(f32x4*)((float*)Cp + (long)(m0 + 128*h + rloc) * ldc + n0 + l64*4) = val;
            }
        }
    }
}

// ---------------------------------------------------------------------------
extern "C" void kernel_launch(void* const* d_in, const int* in_sizes, int n_in,
                              void* d_out, int out_size, void* d_ws, size_t ws_size,
                              hipStream_t stream)
{
    const float* token_reps  = (const float*)d_in[0];
    const int*   span_ids    = (const int*)d_in[1];
    const void*  span_masks  = d_in[2];
    const float* cls_reps    = (const float*)d_in[3];
    const int*   span_widths = (const int*)d_in[4];
    const float* cls_emb     = (const float*)d_in[5];
    const float* in_proj_w   = (const float*)d_in[6];
    const float* in_proj_b   = (const float*)d_in[7];
    const float* out_proj_w  = (const float*)d_in[8];
    const float* out_proj_b  = (const float*)d_in[9];
    const float* width_table = (const float*)d_in[10];
    const float* w1          = (const float*)d_in[11];
    const float* b1          = (const float*)d_in[12];
    const float* w2          = (const float*)d_in[13];
    const float* b2          = (const float*)d_in[14];

    char* ws = (char*)d_ws;
    size_t off = 0;
    auto alloc = [&](size_t bytes)->char*{
        char* p = ws + off;
        off += (bytes + 255) & ~(size_t)255;
        return p;
    };
    int*            flag    = (int*)           alloc(4);
    float*          ubuf    = (float*)         alloc((size_t)(3072 + 4) * 4);
    unsigned short* Xb      = (unsigned short*)alloc((size_t)ROWS_XP * H_ * 2);
    unsigned short* Wv      = (unsigned short*)alloc((size_t)H_ * H_ * 2);
    unsigned short* VB      = (unsigned short*)alloc((size_t)ROWS_XP * H_ * 2);
    float*          SC      = (float*)         alloc((size_t)B_ * NH_ * SP1 * 4);
    int*            keyarr  = (int*)           alloc((size_t)NSPAN * 4);
    unsigned char*  present = (unsigned char*) alloc((size_t)KEYSPACE);
    int*            blockCnt= (int*)           alloc((size_t)162 * 4);
    int*            slotOf  = (int*)           alloc((size_t)KEYSPACE * 4);
    int*            slotPack= (int*)           alloc((size_t)MUPADMAX * 4);
    int*            widthsU = (int*)           alloc((size_t)MUPADMAX * 4);
    int*            slotspan= (int*)           alloc((size_t)NSPAN * 4);
    int*            mu      = (int*)           alloc(8);
    unsigned short* CTXU    = (unsigned short*)alloc((size_t)MUPADMAX * H_ * 2);
    unsigned short* W1a     = (unsigned short*)alloc((size_t)INNER_ * H_ * 2);
    unsigned short* OutT    = (unsigned short*)alloc((size_t)H_ * H_ * 2);
    unsigned short* Wfuse   = (unsigned short*)alloc((size_t)INNER_ * H_ * 2);
    unsigned short* W2b     = (unsigned short*)alloc((size_t)H_ * INNER_ * 2);
    float*          BiasC   = (float*)         alloc((size_t)B_ * INNER_ * 4);
    float*          WC      = (float*)         alloc((size_t)9 * INNER_ * 4);
    unsigned short* H1U     = (unsigned short*)alloc((size_t)MUPADMAX * INNER_ * 2);
    unsigned short* P0      = (unsigned short*)alloc((size_t)MUPADMAX * H_ * 2);
    unsigned short* P1      = CTXU;            // alias: CTXU dead after H1U GEMM
    (void)ws_size; (void)in_sizes; (void)n_in; (void)out_size;

    // conversions + precomputes + present clear + u (one launch)
    // grid: 576+2304+2052+3072+576+768+768+1+162+12 = 10291
    mega_prep<<<10291, 256, 0, stream>>>(
        token_reps, cls_emb, in_proj_w, in_proj_b, out_proj_w, out_proj_b,
        cls_reps, width_table, w1, b1, w2, (const unsigned*)span_masks,
        Xb, Wv, W2b, W1a, OutT, ubuf, BiasC, WC, flag, (unsigned*)present);

    // Wfuse GEMM + VB GEMM + scores + dedup mark (one concurrent launch)
    mid_kernel<<<144 + 102 + 2052 + 64, 256, 0, stream>>>(
        W1a, OutT, Wfuse, Xb, Wv, in_proj_b + 1536, VB,
        token_reps, cls_emb, ubuf, SC,
        span_ids, span_masks, flag, span_widths, keyarr, present);

    // parallel dedup scan (2 launches)
    scanB<<<162, 256, 0, stream>>>((const unsigned*)present, blockCnt);
    scanD<<<162, 256, 0, stream>>>((const unsigned*)present, blockCnt,
                                   slotOf, slotPack, widthsU, mu);

    // unique-span attention + span->slot map
    attn_spanmap<<<MUPADMAX + 86, 192, 0, stream>>>(
        mu, slotPack, SC, VB, CTXU, keyarr, slotOf, slotspan);

    // H1U = relu(CTXU @ Wfused^T + BiasC[b] + WC[width])   (MuPad x 3072, K=768)
    gemm256v4<2, 768, 768><<<(MUPADMAX/256) * (INNER_/256), 512, 0, stream>>>(
        CTXU, Wfuse, BiasC, WC, widthsU, H1U, 768, INNER_, INNER_/256, mu, nullptr);

    // P0/P1 = H1U @ w2^T split-K halves, both bf16 (one launch)
    gemm256v4<3, 3072, 3072><<<2 * (MUPADMAX/256) * (768/256), 512, 0, stream>>>(
        H1U, W2b, nullptr, nullptr, nullptr, P0, 3072, 768, 768/256, mu, P1);

    // expand to all spans: bf2f(P0) + bf2f(P1) + b2
    gather_out3<<<2048, 256, 0, stream>>>(slotspan, P0, P1, b2, (float*)d_out);
}

// Round 12
// 206.753 us; speedup vs baseline: 1.1200x; 1.1200x over previous
//
#include <hip/hip_runtime.h>
#include <hip/hip_bf16.h>
#include <math.h>

// Problem constants
#define B_      4
#define S_      512
#define H_      768
#define NH_     4
#define DH_     192
#define N_      4096          // spans per batch
#define WD_     64
#define INNER_  3072
#define INDIM_  1600
#define SP1     513           // S+1 (CLS prepended)
#define ROWS_X  (B_*SP1)      // 2052
#define ROWS_XP 2176          // padded to multiple of 128
#define NSPAN   (B_*N_)       // 16384
#define KEYS_PB 41472         // 512*9*9 keys per batch
#define KEYSPACE (4*KEYS_PB)  // 165888 = 162*1024
#define MUPADMAX 16640        // 65*256

typedef __attribute__((ext_vector_type(8))) short bf16x8;
typedef __attribute__((ext_vector_type(4))) float f32x4;

__device__ __forceinline__ unsigned short f2bf(float f){
    unsigned u = __builtin_bit_cast(unsigned, f);
    u = u + 0x7FFFu + ((u >> 16) & 1u);   // round-to-nearest-even
    return (unsigned short)(u >> 16);
}
__device__ __forceinline__ float bf2f(unsigned hs){
    return __builtin_bit_cast(float, hs << 16);
}

__device__ __forceinline__ float wave_sum(float p){
    #pragma unroll
    for (int off = 32; off > 0; off >>= 1) p += __shfl_down(p, off);
    return p;
}

// async global->LDS, 16B per lane. lds must be wave-uniform; g is per-lane.
__device__ __forceinline__ void gld16(unsigned short* lds, const unsigned short* g){
    __builtin_amdgcn_global_load_lds(
        (const __attribute__((address_space(1))) unsigned int*)(const void*)g,
        (__attribute__((address_space(3))) unsigned int*)(void*)lds,
        16, 0, 0);
}

__device__ __forceinline__ void wgbar(){
    asm volatile("" ::: "memory");
    __builtin_amdgcn_s_barrier();
    asm volatile("" ::: "memory");
}
#define VMW(n) asm volatile("s_waitcnt vmcnt(" #n ")" ::: "memory")

// ---------------------------------------------------------------------------
// 1. mega prep: conversions + precomputes + present-clear. block ranges:
//    [0,576) Wv | +2304 W2b | +2052 build_x | +3072 W1a | +576 OutT
//    | +192 q | +768 BiasC | +768 WC | +1 mask-detect | +162 present-clear
// ---------------------------------------------------------------------------
__global__ __launch_bounds__(256) void mega_prep(
    const float* __restrict__ token_reps, const float* __restrict__ cls_emb,
    const float* __restrict__ in_proj_w, const float* __restrict__ in_proj_b,
    const float* __restrict__ out_proj_w, const float* __restrict__ out_proj_b,
    const float* __restrict__ cls_reps, const float* __restrict__ wtab,
    const float* __restrict__ w1, const float* __restrict__ b1,
    const float* __restrict__ w2, const unsigned* __restrict__ masks,
    unsigned short* __restrict__ Xb, unsigned short* __restrict__ Wv,
    unsigned short* __restrict__ W2b, unsigned short* __restrict__ W1a,
    unsigned short* __restrict__ OutT, float* __restrict__ qbuf,
    float* __restrict__ BiasC, float* __restrict__ WC, int* __restrict__ flag,
    unsigned* __restrict__ presentW)
{
    int b = blockIdx.x, t = threadIdx.x;
    __shared__ float tile[32][33];
    __shared__ int s_any;
    int wave = t >> 6, lane = t & 63;

    if (b < 576){                                     // Wv conversion (rows 1536..2304)
        long i = (long)b * 256 + t;
        float4 v = ((const float4*)(in_proj_w + (size_t)1536 * H_))[i];
        ushort4 o; o.x = f2bf(v.x); o.y = f2bf(v.y); o.z = f2bf(v.z); o.w = f2bf(v.w);
        ((ushort4*)Wv)[i] = o;
    } else if ((b -= 576) < 2304){                    // W2b conversion
        long i = (long)b * 256 + t;
        float4 v = ((const float4*)w2)[i];
        ushort4 o; o.x = f2bf(v.x); o.y = f2bf(v.y); o.z = f2bf(v.z); o.w = f2bf(v.w);
        ((ushort4*)W2b)[i] = o;
    } else if ((b -= 2304) < 2052){                   // build X
        int r = b;
        int bb = r / SP1, s = r % SP1;
        const float* src = (s == 0) ? cls_emb : &token_reps[((long)bb * S_ + (s - 1)) * H_];
        for (int d = t; d < H_; d += 256)
            Xb[(long)r * H_ + d] = f2bf(src[d]);
    } else if ((b -= 2052) < 3072){                   // w1 cols [0,768) -> W1a
        if (t < 192){
            float4 v = ((const float4*)&w1[(long)b * INDIM_])[t];
            ushort4 o; o.x = f2bf(v.x); o.y = f2bf(v.y); o.z = f2bf(v.z); o.w = f2bf(v.w);
            ((ushort4*)&W1a[(long)b * 768])[t] = o;
        }
    } else if ((b -= 3072) < 576){                    // out_proj_w transpose-convert
        int bx = (b % 24) * 32, by = (b / 24) * 32;
        int tx = t & 31, ty = t >> 5;
        #pragma unroll
        for (int r = 0; r < 32; r += 8)
            tile[ty + r][tx] = out_proj_w[(long)(by + ty + r) * 768 + bx + tx];
        __syncthreads();
        #pragma unroll
        for (int r = 0; r < 32; r += 8)
            OutT[(long)(bx + ty + r) * 768 + by + tx] = f2bf(tile[tx][ty + r]);
    } else if ((b -= 576) < 192){                     // q projection
        int j = b * 4 + wave;
        const float* wr = &in_proj_w[(long)j * H_];
        float p = 0.f;
        #pragma unroll
        for (int i = 0; i < 12; ++i) p += cls_emb[lane + 64*i] * wr[lane + 64*i];
        p = wave_sum(p);
        if (lane == 0) qbuf[j] = p + in_proj_b[j];
    } else if ((b -= 192) < 768){                     // BiasC
        int i = b * 4 + wave;
        const float* row = &w1[(long)i * INDIM_];
        float p0 = 0.f, pb0 = 0.f, pb1 = 0.f, pb2 = 0.f, pb3 = 0.f;
        #pragma unroll
        for (int k0 = 0; k0 < 12; ++k0){
            int k = lane + 64*k0;
            p0 += out_proj_b[k] * row[k];
            float rv = row[832 + k];
            pb0 += cls_reps[0*H_ + k] * rv;
            pb1 += cls_reps[1*H_ + k] * rv;
            pb2 += cls_reps[2*H_ + k] * rv;
            pb3 += cls_reps[3*H_ + k] * rv;
        }
        p0 = wave_sum(p0); pb0 = wave_sum(pb0); pb1 = wave_sum(pb1);
        pb2 = wave_sum(pb2); pb3 = wave_sum(pb3);
        if (lane == 0){
            float base = b1[i] + p0;
            BiasC[0*INNER_ + i] = base + pb0;
            BiasC[1*INNER_ + i] = base + pb1;
            BiasC[2*INNER_ + i] = base + pb2;
            BiasC[3*INNER_ + i] = base + pb3;
        }
    } else if ((b -= 768) < 768){                     // WC
        int i = b * 4 + wave;
        float rv = w1[(long)i * INDIM_ + 768 + lane];
        #pragma unroll
        for (int w = 0; w < 9; ++w){
            float p = wave_sum(wtab[w * WD_ + lane] * rv);
            if (lane == 0) WC[w * INNER_ + i] = p;
        }
    } else if ((b -= 768) < 1){                       // mask encoding detect
        if (t == 0) s_any = 0;
        __syncthreads();
        int any = 0;
        for (int i = t; i < 4096; i += 256){
            unsigned v = masks[i];
            if (!(v == 0u || v == 1u || v == 0x3F800000u)) any = 1;
        }
        if (any) s_any = 1;
        __syncthreads();
        if (t == 0) *flag = s_any;
    } else {                                          // present clear (162 blocks)
        b -= 1;
        presentW[b * 256 + t] = 0u;
    }
}

// ---------------------------------------------------------------------------
// 2. u_mark: blocks [0,12) u-precompute; [12,76) dedup key mark.
// ---------------------------------------------------------------------------
__global__ __launch_bounds__(256) void u_mark(
    const float* __restrict__ q, const float* __restrict__ in_proj_w,
    const float* __restrict__ in_proj_b, float* __restrict__ u,
    const int* __restrict__ span_ids, const void* __restrict__ masks,
    const int* __restrict__ flag, const int* __restrict__ span_widths,
    int* __restrict__ keyarr, unsigned char* __restrict__ present)
{
    int blk = blockIdx.x, t = threadIdx.x;
    if (blk < 12){
        int idx = blk * 256 + t;
        int h = idx / 768, k = idx % 768;
        float s = 0.f;
        for (int j = 0; j < 192; ++j)
            s += q[h*192 + j] * in_proj_w[(long)(768 + h*192 + j) * 768 + k];
        u[idx] = s;
        if (idx < 4){
            float c = 0.f;
            for (int j = 0; j < 192; ++j) c += q[idx*192 + j] * in_proj_b[768 + idx*192 + j];
            u[3072 + idx] = c;
        }
    } else {
        int span = (blk - 12) * 256 + t;
        int start = span_ids[span*2], end = span_ids[span*2+1];
        bool sm = (*flag == 0) ? (((const unsigned*)masks)[span] != 0u)
                               : (((const unsigned char*)masks)[span] != 0);
        int cnt = sm ? (end - start) : 0;
        if (cnt < 0) cnt = 0;
        if (cnt > 8) cnt = 8;
        if (start < 0) start = 0;
        if (start > 511) start = 511;
        if (start + cnt > S_) cnt = S_ - start;
        if (cnt == 0) start = 0;                     // masked-span collapse
        int w = span_widths[span];
        w = (w < 0) ? 0 : ((w > 8) ? 8 : w);
        int b = span >> 12;
        int key = b * KEYS_PB + (start * 9 + cnt) * 9 + w;
        keyarr[span] = key;
        present[key] = 1;
    }
}

// ---------------------------------------------------------------------------
// 3. gemm97 device body (128x128, BK=32, gld16 staging) — used by mid_kernel
// ---------------------------------------------------------------------------
template<int EPI>
__device__ __forceinline__ void gemm97_body(
    int bid, int nwg,
    const unsigned short* __restrict__ A, const unsigned short* __restrict__ Bm,
    const float* __restrict__ biasA, void* __restrict__ Cp,
    int M, int N, int K, int lda, int ldb, int ldc, int nbx,
    unsigned short* As, unsigned short* Bs)
{
    const int t = threadIdx.x, lane = t & 63, wave = t >> 6;
    const int wr = wave >> 1, wcid = wave & 1;

    int swz = ((nwg & 7) == 0) ? ((bid & 7) * (nwg >> 3) + (bid >> 3)) : bid;
    const int m0 = (swz / nbx) * 128;
    const int n0 = (swz % nbx) * 128;

    f32x4 acc[4][4];
    #pragma unroll
    for (int i = 0; i < 4; ++i)
        #pragma unroll
        for (int j = 0; j < 4; ++j)
            acc[i][j] = (f32x4){0.f, 0.f, 0.f, 0.f};

    const unsigned short* gA = A + (long)(m0 + wave*32 + (lane >> 2)) * lda + (lane & 3) * 8;
    const unsigned short* gB = Bm + (long)(n0 + wave*32 + (lane >> 2)) * ldb + (lane & 3) * 8;
    unsigned short* lA = &As[wave * 32 * 32];
    unsigned short* lB = &Bs[wave * 32 * 32];
    const long a16 = (long)16 * lda, b16 = (long)16 * ldb;

    for (int k0 = 0; k0 < K; k0 += 32){
        gld16(lA,       gA + k0);
        gld16(lA + 512, gA + a16 + k0);
        gld16(lB,       gB + k0);
        gld16(lB + 512, gB + b16 + k0);
        __syncthreads();

        bf16x8 af[4], bfr[4];
        #pragma unroll
        for (int f = 0; f < 4; ++f){
            af[f]  = *(const bf16x8*)&As[(wr*64 + f*16 + (lane & 15)) * 32 + (lane >> 4) * 8];
            bfr[f] = *(const bf16x8*)&Bs[(wcid*64 + f*16 + (lane & 15)) * 32 + (lane >> 4) * 8];
        }
        #pragma unroll
        for (int i = 0; i < 4; ++i)
            #pragma unroll
            for (int j = 0; j < 4; ++j)
                acc[i][j] = __builtin_amdgcn_mfma_f32_16x16x32_bf16(af[i], bfr[j], acc[i][j], 0, 0, 0);
        __syncthreads();
    }

    const int r0 = (lane >> 4) * 4;
    const int cc = lane & 15;
    #pragma unroll
    for (int i = 0; i < 4; ++i){
        int rowb = m0 + wr*64 + i*16 + r0;
        #pragma unroll
        for (int j = 0; j < 4; ++j){
            int col = n0 + wcid*64 + j*16 + cc;
            float cb = biasA ? biasA[col] : 0.f;
            #pragma unroll
            for (int r = 0; r < 4; ++r){
                long o = (long)(rowb + r) * ldc + col;
                float v = acc[i][j][r] + cb;
                if (EPI == 1) ((unsigned short*)Cp)[o] = f2bf(v);
                else          ((float*)Cp)[o] = v;
            }
        }
    }
}

// ---------------------------------------------------------------------------
// 4. mid kernel: [0,144) Wfuse GEMM | [144,246) VB GEMM | [246,2298) scores2
// ---------------------------------------------------------------------------
__global__ __launch_bounds__(256) void mid_kernel(
    const unsigned short* __restrict__ W1a, const unsigned short* __restrict__ OutT,
    unsigned short* __restrict__ Wfuse,
    const unsigned short* __restrict__ Xb, const unsigned short* __restrict__ Wv,
    const float* __restrict__ bv, unsigned short* __restrict__ VB,
    const float* __restrict__ token_reps, const float* __restrict__ cls_emb,
    const float* __restrict__ u, float* __restrict__ SC)
{
    __shared__ unsigned short As[128 * 32];
    __shared__ unsigned short Bs[128 * 32];
    int blk = blockIdx.x;
    if (blk < 144){
        gemm97_body<1>(blk, 144, W1a, OutT, nullptr, Wfuse,
                       INNER_, 768, 768, 768, 768, 768, 6, As, Bs);
    } else if (blk < 246){
        gemm97_body<1>(blk - 144, 102, Xb, Wv, bv, VB,
                       ROWS_XP, 768, 768, 768, 768, 768, 6, As, Bs);
    } else {
        int r = blk - 246;                            // 0..2051
        int b = r / SP1, s = r % SP1;
        const float* src = (s == 0) ? cls_emb : &token_reps[((long)b * S_ + (s - 1)) * H_];
        int h = threadIdx.x >> 6, lane = threadIdx.x & 63;
        float p = 0.f;
        #pragma unroll
        for (int i = 0; i < 12; ++i) p += src[lane + 64*i] * u[h*768 + lane + 64*i];
        p = wave_sum(p);
        if (lane == 0){
            const float scale = 0.0721687836487032f;  // 1/sqrt(192)
            SC[((long)(b * NH_ + h)) * SP1 + s] = (p + u[3072 + h]) * scale;
        }
    }
}

// ---------------------------------------------------------------------------
// 5. scan: B (per-block counts) then D (local re-scan of counts + emit + mu)
// ---------------------------------------------------------------------------
__global__ __launch_bounds__(256) void scanB(const unsigned* __restrict__ present4,
                                             int* __restrict__ blockCnt){
    __shared__ int sh[256];
    int blk = blockIdx.x, t = threadIdx.x;
    unsigned w = present4[blk*256 + t];
    int c = (w & 1) + ((w >> 8) & 1) + ((w >> 16) & 1) + ((w >> 24) & 1);
    sh[t] = c; __syncthreads();
    for (int off = 128; off > 0; off >>= 1){
        if (t < off) sh[t] += sh[t + off];
        __syncthreads();
    }
    if (t == 0) blockCnt[blk] = sh[0];
}

__global__ __launch_bounds__(256) void scanD(const unsigned* __restrict__ present4,
                                             const int* __restrict__ blockCnt,
                                             int* __restrict__ slotOf, int* __restrict__ slotPack,
                                             int* __restrict__ widthsU, int* __restrict__ mu){
    __shared__ int offs[256];
    __shared__ int sh[256];
    int blk = blockIdx.x, t = threadIdx.x;
    int v = (t < 162) ? blockCnt[t] : 0;
    offs[t] = v; __syncthreads();
    for (int off = 1; off < 256; off <<= 1){
        int add = (t >= off) ? offs[t - off] : 0;
        __syncthreads();
        offs[t] += add;
        __syncthreads();
    }
    if (blk == 0 && t == 161){ mu[0] = offs[161]; mu[1] = (offs[161] + 255) & ~255; }
    int blockBase = (blk == 0) ? 0 : offs[blk - 1];
    unsigned w = present4[blk*256 + t];
    int c = (w & 1) + ((w >> 8) & 1) + ((w >> 16) & 1) + ((w >> 24) & 1);
    sh[t] = c; __syncthreads();
    for (int off = 1; off < 256; off <<= 1){
        int add = (t >= off) ? sh[t - off] : 0;
        __syncthreads();
        sh[t] += add;
        __syncthreads();
    }
    int slot = blockBase + sh[t] - c;
    #pragma unroll
    for (int i = 0; i < 4; ++i){
        if ((w >> (8*i)) & 1){
            int k = blk*1024 + t*4 + i;
            slotOf[k] = slot;
            int b = k / KEYS_PB, kl = k % KEYS_PB;
            int width = kl % 9, sc2 = kl / 9;
            int cnt = sc2 % 9, start = sc2 / 9;
            slotPack[slot] = start | (cnt << 9) | (width << 13) | (b << 17);
            widthsU[slot]  = width | (b << 4);
            slot++;
        }
    }
}

// ---------------------------------------------------------------------------
// 6. attn_spanmap: blocks [0,16640) unique-span attention; rest spanmap
// ---------------------------------------------------------------------------
__global__ __launch_bounds__(192) void attn_spanmap(
    const int* __restrict__ mu, const int* __restrict__ slotPack,
    const float* __restrict__ SC, const unsigned short* __restrict__ VB,
    unsigned short* __restrict__ CTXU,
    const int* __restrict__ keyarr, const int* __restrict__ slotOf,
    int* __restrict__ slotspan)
{
    int blk = blockIdx.x, t = threadIdx.x;
    if (blk >= MUPADMAX){                            // spanmap part
        int s = (blk - MUPADMAX) * 192 + t;
        if (s < NSPAN) slotspan[s] = slotOf[keyarr[s]];
        return;
    }
    int slot = blk;
    if (slot >= mu[0]) return;
    int pk = slotPack[slot];
    int start = pk & 511, cnt = (pk >> 9) & 15, b = (pk >> 17) & 3;
    __shared__ float w_sh[NH_][12];

    if (t < NH_){
        int h = t;
        const float* sc = &SC[((long)(b * NH_ + h)) * SP1];
        float m = sc[0];
        for (int j = 0; j < cnt; ++j) m = fmaxf(m, sc[1 + start + j]);
        float e0 = expf(sc[0] - m), sum = e0;
        float ej[8];
        for (int j = 0; j < cnt; ++j){ ej[j] = expf(sc[1 + start + j] - m); sum += ej[j]; }
        float inv = 1.f / sum;
        w_sh[h][0] = e0 * inv;
        for (int j = 0; j < cnt; ++j) w_sh[h][1 + j] = ej[j] * inv;
    }
    __syncthreads();

    long ctxbase = (long)slot * H_;
    const unsigned short* V0 = VB + (long)(b * SP1) * 768;
    #pragma unroll
    for (int i = 0; i < 2; ++i){
        int p = t + 192 * i;
        int d = p * 2;
        int h = d / DH_;
        float w0 = w_sh[h][0];
        unsigned v = ((const unsigned*)V0)[p];
        float a0 = w0 * bf2f(v & 0xffffu), a1 = w0 * bf2f(v >> 16);
        for (int j = 0; j < cnt; ++j){
            unsigned vv = *(const unsigned*)(V0 + (long)(1 + start + j) * 768 + d);
            float wj = w_sh[h][1 + j];
            a0 += wj * bf2f(vv & 0xffffu);
            a1 += wj * bf2f(vv >> 16);
        }
        ((unsigned*)(CTXU + ctxbase))[p] = (unsigned)f2bf(a0) | ((unsigned)f2bf(a1) << 16);
    }
}

// ---------------------------------------------------------------------------
// 7. gather_out3: out[span] = bf2f(P0[slot]) + bf2f(P1[slot]) + b2
// ---------------------------------------------------------------------------
__global__ __launch_bounds__(256) void gather_out3(
    const int* __restrict__ slotspan, const unsigned short* __restrict__ P0,
    const unsigned short* __restrict__ P1, const float* __restrict__ b2,
    float* __restrict__ out)
{
    const long total = (long)NSPAN * 192;            // float4 count
    long stride = (long)gridDim.x * 256;
    for (long idx = (long)blockIdx.x * 256 + threadIdx.x; idx < total; idx += stride){
        long s = idx / 192, d = idx % 192;
        long so = (long)slotspan[s] * 192 + d;
        ushort4 p0 = ((const ushort4*)P0)[so];
        ushort4 p1 = ((const ushort4*)P1)[so];
        float4 bb = ((const float4*)b2)[d];
        float4 o;
        o.x = bf2f(p0.x) + bf2f(p1.x) + bb.x;
        o.y = bf2f(p0.y) + bf2f(p1.y) + bb.y;
        o.z = bf2f(p0.z) + bf2f(p1.z) + bb.z;
        o.w = bf2f(p0.w) + bf2f(p1.w) + bb.w;
        ((float4*)out)[idx] = o;
    }
}

// ---------------------------------------------------------------------------
// 8. 256x256 GEMM v4 (one-phase-ahead prefetch). Early-exit on mu BEFORE the
//    XCD swizzle; bijective m204 swizzle over the active prefix.
//    EPI 2: bf16 out + relu + per-row packed width|batch bias
//    EPI 3: split-K dual; BOTH halves bf16: sp=0 -> Cp, sp=1 -> Cp1
// ---------------------------------------------------------------------------
template<int EPI, int LDA_, int LDB_>
__global__ __launch_bounds__(512, 2) void gemm256v4(
    const unsigned short* __restrict__ A, const unsigned short* __restrict__ Bm,
    const float* __restrict__ biasA, const float* __restrict__ biasB,
    const int* __restrict__ widths, void* __restrict__ Cp,
    int K, int ldc, int nbx, const int* __restrict__ mu,
    unsigned short* __restrict__ Cp1)
{
    __shared__ __align__(16) unsigned char lds[131072];
    const int t = threadIdx.x, lane = t & 63;
    const int wave = t >> 6;
    const int wr = wave >> 2, wc = wave & 3;      // 2M x 4N waves

    int nwg = gridDim.x, bid = blockIdx.x;
    int sp = 0;
    if (EPI == 3){
        int nh = nwg >> 1;
        sp = (bid >= nh) ? 1 : 0;
        bid -= sp * nh;
        nwg = nh;
    }
    if (mu){                                      // exit FIRST, swizzle over actives
        int nact = (mu[1] >> 8) * nbx;
        if (bid >= nact) return;
        nwg = nact;
    }
    // bijective m204 XCD swizzle over the active prefix
    int q = nwg >> 3, rr = nwg & 7;
    int xcd = bid & 7, idx8 = bid >> 3;
    int swz = (xcd < rr ? xcd * (q + 1) : rr * (q + 1) + (xcd - rr) * q) + idx8;
    const int m0 = (swz / nbx) * 256;
    const int n0 = (swz % nbx) * 256;

    const int Keff = (EPI == 3) ? (K >> 1) : K;
    const unsigned short* Ab = A + (EPI == 3 ? (long)sp * Keff : 0);
    const unsigned short* Bb = Bm + (EPI == 3 ? (long)sp * Keff : 0);

    // staging (source pre-swizzled; LDS dest linear, wave-private 1KB slices)
    const int rQ = t >> 3;
    const int cswz = ((t & 7) ^ (rQ & 7)) << 3;
    const unsigned short* sA = Ab + (long)(m0 + rQ) * LDA_ + cswz;
    const unsigned short* sB = Bb + (long)(n0 + ((rQ >> 5) * 64 + (rQ & 31))) * LDB_ + cswz;
    const int wsl = wave * 1024;

    // ds_read bases (16x16 fragments, conflict-free swizzle)
    const int aRow = (wr * 64 + (lane & 15)) * 128;
    const int bRow = (wc * 32 + (lane & 15)) * 128;
    const int pcl0 = (((lane >> 4) * 16)) ^ ((lane & 7) << 4);
    const int pcl1 = (64 + ((lane >> 4) * 16)) ^ ((lane & 7) << 4);

    f32x4 acc[8][4];
    #pragma unroll
    for (int i = 0; i < 8; ++i)
        #pragma unroll
        for (int j = 0; j < 4; ++j)
            acc[i][j] = (f32x4){0.f, 0.f, 0.f, 0.f};

    const int KT = Keff >> 6;
    bf16x8 aL[4][2], aH[4][2], bE[2][2], bO[2][2];

#define STG_(off, src) gld16((unsigned short*)(void*)(lds + (off) + wsl), (src))
#define RD_AL(fi, base) { aL[fi][0] = *(const bf16x8*)(lds + (base) + aRow + (fi)*2048 + pcl0); \
                          aL[fi][1] = *(const bf16x8*)(lds + (base) + aRow + (fi)*2048 + pcl1); }
#define RD_AH(fi, base) { aH[fi][0] = *(const bf16x8*)(lds + (base) + 16384 + aRow + (fi)*2048 + pcl0); \
                          aH[fi][1] = *(const bf16x8*)(lds + (base) + 16384 + aRow + (fi)*2048 + pcl1); }
#define RD_BE(jj, base) { bE[jj][0] = *(const bf16x8*)(lds + (base) + (jj)*2048 + bRow + pcl0); \
                          bE[jj][1] = *(const bf16x8*)(lds + (base) + (jj)*2048 + bRow + pcl1); }
#define RD_BO(jj, base) { bO[jj][0] = *(const bf16x8*)(lds + (base) + 16384 + (jj)*2048 + bRow + pcl0); \
                          bO[jj][1] = *(const bf16x8*)(lds + (base) + 16384 + (jj)*2048 + bRow + pcl1); }
#define Q_MFMA(AR, BR, I0, J0) \
    __builtin_amdgcn_s_setprio(1); \
    _Pragma("unroll") \
    for (int i = 0; i < 4; ++i) \
        _Pragma("unroll") \
        for (int j = 0; j < 2; ++j){ \
            acc[(I0)+i][(J0)+j] = __builtin_amdgcn_mfma_f32_16x16x32_bf16(AR[i][0], BR[j][0], acc[(I0)+i][(J0)+j], 0, 0, 0); \
            acc[(I0)+i][(J0)+j] = __builtin_amdgcn_mfma_f32_16x16x32_bf16(AR[i][1], BR[j][1], acc[(I0)+i][(J0)+j], 0, 0, 0); \
        } \
    __builtin_amdgcn_s_setprio(0);

    // ---- prologue: stage K-tile 0 (FIFO U1,U2,U3,U4); read aL[0,1], bE ----
    STG_(0,             sA);
    STG_(8192,          sA + 128 * LDA_);
    STG_(65536,         sB);
    STG_(65536 + 8192,  sB + 128 * LDB_);
    STG_(65536 + 16384, sB + 32 * LDB_);
    STG_(65536 + 24576, sB + 160 * LDB_);
    STG_(16384,         sA + 64 * LDA_);
    STG_(24576,         sA + 192 * LDA_);
    VMW(4);
    wgbar();
    RD_AL(0, 0u); RD_AL(1, 0u);
    RD_BE(0, 65536u); RD_BE(1, 65536u);

    for (int kt = 0; kt < KT - 1; ++kt){
        const unsigned rA = (unsigned)(kt & 1) * 32768u;
        const unsigned rB = 65536u + rA;
        const unsigned wA = rA ^ 32768u;
        const unsigned wB = 65536u + wA;
        const unsigned short* pA = sA + (long)(kt + 1) * 64;
        const unsigned short* pB = sB + (long)(kt + 1) * 64;

        // ===== P1
        VMW(2);
        STG_(wA, pA); STG_(wA + 8192, pA + 128 * LDA_);
        wgbar();
        RD_AL(2, rA); RD_AL(3, rA);
        RD_BO(0, rB); RD_BO(1, rB);
        Q_MFMA(aL, bE, 0, 0);

        // ===== P2
        VMW(2);
        STG_(wB, pB); STG_(wB + 8192, pB + 128 * LDB_);
        wgbar();
        RD_AH(0, rA); RD_AH(1, rA);
        Q_MFMA(aL, bO, 0, 2);

        // ===== P3
        STG_(wB + 16384, pB + 32 * LDB_); STG_(wB + 24576, pB + 160 * LDB_);
        wgbar();
        RD_AH(2, rA); RD_AH(3, rA);
        Q_MFMA(aH, bE, 4, 0);

        // ===== P4
        VMW(2);
        STG_(wA + 16384, pA + 64 * LDA_); STG_(wA + 24576, pA + 192 * LDA_);
        wgbar();
        RD_AL(0, wA); RD_AL(1, wA);
        RD_BE(0, wB); RD_BE(1, wB);
        Q_MFMA(aH, bO, 4, 2);
    }

    // ---- tail
    {
        const unsigned rA = (unsigned)((KT - 1) & 1) * 32768u;
        const unsigned rB = 65536u + rA;
        VMW(2);
        wgbar();
        RD_AL(2, rA); RD_AL(3, rA);
        RD_BO(0, rB); RD_BO(1, rB);
        Q_MFMA(aL, bE, 0, 0);
        VMW(0);
        wgbar();
        RD_AH(0, rA); RD_AH(1, rA);
        Q_MFMA(aL, bO, 0, 2);
        RD_AH(2, rA); RD_AH(3, rA);
        Q_MFMA(aH, bE, 4, 0);
        Q_MFMA(aH, bO, 4, 2);
    }
#undef STG_
#undef RD_AL
#undef RD_AH
#undef RD_BE
#undef RD_BO
#undef Q_MFMA

    // ---- epilogue via LDS routing; row = wr*128 + mq*64 + i*16 + r0 + r
    const int r0 = (lane >> 4) * 4;
    const int cc = lane & 15;
    const int Nn = nbx * 256;

    if (EPI == 2){
        wgbar();
        #pragma unroll
        for (int mq = 0; mq < 2; ++mq){
            #pragma unroll
            for (int i = 0; i < 4; ++i){
                #pragma unroll
                for (int r = 0; r < 4; ++r){
                    int row = wr*128 + mq*64 + i*16 + r0 + r;   // local 0..255
                    int wb = widths[m0 + row];                  // packed wv | b<<4
                    int wv = wb & 15, bb = (wb >> 4) & 3;
                    const float* bcl = biasA + (long)bb * Nn;
                    const float* wcb = biasB + (long)wv * Nn;
                    unsigned key = (unsigned)((row & 7) << 4);
                    unsigned rbase = (unsigned)row * 512u;
                    #pragma unroll
                    for (int j = 0; j < 4; ++j){
                        int col = wc*64 + j*16 + cc;
                        float v = acc[4*mq + i][j][r] + bcl[n0 + col] + wcb[n0 + col];
                        v = fmaxf(v, 0.f);
                        *(unsigned short*)(lds + rbase + (((unsigned)col * 2u) ^ key)) = f2bf(v);
                    }
                }
            }
        }
        wgbar();
        #pragma unroll
        for (int k = 0; k < 16; ++k){
            int row = (t >> 5) + k*16;
            int l32 = t & 31;
            bf16x8 val = *(const bf16x8*)(lds + (unsigned)row*512u
                             + (((unsigned)l32*16u) ^ ((unsigned)(row & 7) << 4)));
            *(bf16x8*)((unsigned short*)Cp + (long)(m0 + row) * ldc + n0 + l32*8) = val;
        }
    } else if (EPI == 3){
        // bf16 partial (both halves), no bias, no relu
        unsigned short* dst = sp ? Cp1 : (unsigned short*)Cp;
        wgbar();
        #pragma unroll
        for (int mq = 0; mq < 2; ++mq){
            #pragma unroll
            for (int i = 0; i < 4; ++i){
                #pragma unroll
                for (int r = 0; r < 4; ++r){
                    int row = wr*128 + mq*64 + i*16 + r0 + r;
                    unsigned key = (unsigned)((row & 7) << 4);
                    unsigned rbase = (unsigned)row * 512u;
                    #pragma unroll
                    for (int j = 0; j < 4; ++j){
                        int col = wc*64 + j*16 + cc;
                        *(unsigned short*)(lds + rbase + (((unsigned)col * 2u) ^ key))
                            = f2bf(acc[4*mq + i][j][r]);
                    }
                }
            }
        }
        wgbar();
        #pragma unroll
        for (int k = 0; k < 16; ++k){
            int row = (t >> 5) + k*16;
            int l32 = t & 31;
            bf16x8 val = *(const bf16x8*)(lds + (unsigned)row*512u
                             + (((unsigned)l32*16u) ^ ((unsigned)(row & 7) << 4)));
            *(bf16x8*)(dst + (long)(m0 + row) * ldc + n0 + l32*8) = val;
        }
    } else {
        // f32 out: two half-tile passes (wr==h owns storage rows)
        #pragma unroll
        for (int h = 0; h < 2; ++h){
            wgbar();
            if (wr == h){
                #pragma unroll
                for (int mq = 0; mq < 2; ++mq){
                    #pragma unroll
                    for (int i = 0; i < 4; ++i){
                        #pragma unroll
                        for (int r = 0; r < 4; ++r){
                            int rloc = mq*64 + i*16 + r0 + r;
                            unsigned key = (unsigned)((rloc & 7) << 4);
                            unsigned rbase = (unsigned)rloc * 1024u;
                            #pragma unroll
                            for (int j = 0; j < 4; ++j){
                                int col = wc*64 + j*16 + cc;
                                float v = acc[4*mq + i][j][r] + (biasA ? biasA[n0 + col] : 0.f);
                                *(float*)(lds + rbase + (((unsigned)col * 4u) ^ key)) = v;
                            }
                        }
                    }
                }
            }
            wgbar();
            #pragma unroll
            for (int k = 0; k < 16; ++k){
                int rloc = (t >> 6) + k*8;
                int l64 = t & 63;
                f32x4 val = *(const f32x4*)(lds + (unsigned)rloc*1024u
                                 + (((unsigned)l64*16u) ^ ((unsigned)(rloc & 7) << 4)));
                *(f32x4*)((float*)Cp + (long)(m0 + 128*h + rloc) * ldc + n0 + l64*4) = val;
            }
        }
    }
}

// ---------------------------------------------------------------------------
extern "C" void kernel_launch(void* const* d_in, const int* in_sizes, int n_in,
                              void* d_out, int out_size, void* d_ws, size_t ws_size,
                              hipStream_t stream)
{
    const float* token_reps  = (const float*)d_in[0];
    const int*   span_ids    = (const int*)d_in[1];
    const void*  span_masks  = d_in[2];
    const float* cls_reps    = (const float*)d_in[3];
    const int*   span_widths = (const int*)d_in[4];
    const float* cls_emb     = (const float*)d_in[5];
    const float* in_proj_w   = (const float*)d_in[6];
    const float* in_proj_b   = (const float*)d_in[7];
    const float* out_proj_w  = (const float*)d_in[8];
    const float* out_proj_b  = (const float*)d_in[9];
    const float* width_table = (const float*)d_in[10];
    const float* w1          = (const float*)d_in[11];
    const float* b1          = (const float*)d_in[12];
    const float* w2          = (const float*)d_in[13];
    const float* b2          = (const float*)d_in[14];

    char* ws = (char*)d_ws;
    size_t off = 0;
    auto alloc = [&](size_t bytes)->char*{
        char* p = ws + off;
        off += (bytes + 255) & ~(size_t)255;
        return p;
    };
    int*            flag    = (int*)           alloc(4);
    float*          qbuf    = (float*)         alloc((size_t)H_ * 4);
    float*          ubuf    = (float*)         alloc((size_t)(3072 + 4) * 4);
    unsigned short* Xb      = (unsigned short*)alloc((size_t)ROWS_XP * H_ * 2);
    unsigned short* Wv      = (unsigned short*)alloc((size_t)H_ * H_ * 2);
    unsigned short* VB      = (unsigned short*)alloc((size_t)ROWS_XP * H_ * 2);
    float*          SC      = (float*)         alloc((size_t)B_ * NH_ * SP1 * 4);
    int*            keyarr  = (int*)           alloc((size_t)NSPAN * 4);
    unsigned char*  present = (unsigned char*) alloc((size_t)KEYSPACE);
    int*            blockCnt= (int*)           alloc((size_t)162 * 4);
    int*            slotOf  = (int*)           alloc((size_t)KEYSPACE * 4);
    int*            slotPack= (int*)           alloc((size_t)MUPADMAX * 4);
    int*            widthsU = (int*)           alloc((size_t)MUPADMAX * 4);
    int*            slotspan= (int*)           alloc((size_t)NSPAN * 4);
    int*            mu      = (int*)           alloc(8);
    unsigned short* CTXU    = (unsigned short*)alloc((size_t)MUPADMAX * H_ * 2);
    unsigned short* W1a     = (unsigned short*)alloc((size_t)INNER_ * H_ * 2);
    unsigned short* OutT    = (unsigned short*)alloc((size_t)H_ * H_ * 2);
    unsigned short* Wfuse   = (unsigned short*)alloc((size_t)INNER_ * H_ * 2);
    unsigned short* W2b     = (unsigned short*)alloc((size_t)H_ * INNER_ * 2);
    float*          BiasC   = (float*)         alloc((size_t)B_ * INNER_ * 4);
    float*          WC      = (float*)         alloc((size_t)9 * INNER_ * 4);
    unsigned short* H1U     = (unsigned short*)alloc((size_t)MUPADMAX * INNER_ * 2);
    unsigned short* P0      = (unsigned short*)alloc((size_t)MUPADMAX * H_ * 2);
    unsigned short* P1      = CTXU;            // alias: CTXU dead after H1U GEMM
    (void)ws_size; (void)in_sizes; (void)n_in; (void)out_size;

    // conversions + precomputes + present clear (one launch)
    mega_prep<<<576 + 2304 + 2052 + 3072 + 576 + 192 + 768 + 768 + 1 + 162, 256, 0, stream>>>(
        token_reps, cls_emb, in_proj_w, in_proj_b, out_proj_w, out_proj_b,
        cls_reps, width_table, w1, b1, w2, (const unsigned*)span_masks,
        Xb, Wv, W2b, W1a, OutT, qbuf, BiasC, WC, flag, (unsigned*)present);

    // u precompute + dedup key mark
    u_mark<<<76, 256, 0, stream>>>(qbuf, in_proj_w, in_proj_b, ubuf,
                                   span_ids, span_masks, flag, span_widths,
                                   keyarr, present);

    // Wfuse GEMM + VB GEMM + scores (one concurrent launch)
    mid_kernel<<<144 + 102 + 2052, 256, 0, stream>>>(
        W1a, OutT, Wfuse, Xb, Wv, in_proj_b + 1536, VB,
        token_reps, cls_emb, ubuf, SC);

    // parallel dedup scan (2 launches)
    scanB<<<162, 256, 0, stream>>>((const unsigned*)present, blockCnt);
    scanD<<<162, 256, 0, stream>>>((const unsigned*)present, blockCnt,
                                   slotOf, slotPack, widthsU, mu);

    // unique-span attention + span->slot map
    attn_spanmap<<<MUPADMAX + 86, 192, 0, stream>>>(
        mu, slotPack, SC, VB, CTXU, keyarr, slotOf, slotspan);

    // H1U = relu(CTXU @ Wfused^T + BiasC[b] + WC[width])   (MuPad x 3072, K=768)
    gemm256v4<2, 768, 768><<<(MUPADMAX/256) * (INNER_/256), 512, 0, stream>>>(
        CTXU, Wfuse, BiasC, WC, widthsU, H1U, 768, INNER_, INNER_/256, mu, nullptr);

    // P0/P1 = H1U @ w2^T split-K halves, both bf16 (one launch)
    gemm256v4<3, 3072, 3072><<<2 * (MUPADMAX/256) * (768/256), 512, 0, stream>>>(
        H1U, W2b, nullptr, nullptr, nullptr, P0, 3072, 768, 768/256, mu, P1);

    // expand to all spans: bf2f(P0) + bf2f(P1) + b2
    gather_out3<<<2048, 256, 0, stream>>>(slotspan, P0, P1, b2, (float*)d_out);
}